// Round 4
// baseline (11158.772 us; speedup 1.0000x reference)
//
#include <hip/hip_runtime.h>
#include <math.h>

#define N 1024
#define NN (N*N)

// ---------- wave argmax (64 lanes), lowest-index tie-break ----------
__device__ __forceinline__ void wave_argmax(float& best, int& bi) {
  #pragma unroll
  for (int off = 32; off > 0; off >>= 1) {
    float ob = __shfl_down(best, off);
    int   oi = __shfl_down(bi, off);
    if (ob > best || (ob == best && oi < bi)) { best = ob; bi = oi; }
  }
}

// ======================= init =======================
__global__ void init_kernel(double* scores) {
  int t = threadIdx.x;
  if (t < 16) scores[t] = 0.0;
}

// ======================= copy x -> LU workspace =======================
__global__ __launch_bounds__(256) void copy_kernel(const float4* __restrict__ src,
                                                   float4* __restrict__ dst) {
  int i = blockIdx.x * 256 + threadIdx.x;   // grid sized exactly: 16M floats / 4
  dst[i] = src[i];
}

// ======================= LU panel factorization (width 32), register-resident ====
// One block of 512 threads per matrix. Thread t owns panel-local row slots 2t and
// 2t+1 (32 floats each) in REGISTERS (fully unrolled j-loop -> static indexing).
// Per j-step: owners of slot j and pivot slot p publish full rows to LDS bufJ/bufP
// (bufP doubles as the broadcast U-row), 2 barriers total; next-column pivot is
// scanned during the rank-1 update; argmax combine done redundantly by all threads.
// Pivot choice / tie-break / ipiv semantics identical to the verified R3 kernel.
__global__ __launch_bounds__(512) void panel_kernel(float* __restrict__ lu,
                                                    int* __restrict__ ipiv,
                                                    double* __restrict__ scores,
                                                    int c0) {
  __shared__ __align__(16) float bufJ[32];
  __shared__ __align__(16) float bufP[32];
  __shared__ float redv[8];
  __shared__ int   redi[8];
  const int m = blockIdx.x;
  float* A = lu + (size_t)m * NN;
  const int R = N - c0;
  const int tid = threadIdx.x;
  const int s0 = tid * 2, s1 = tid * 2 + 1;   // owned panel-local row slots
  const bool h0 = s0 < R, h1 = s1 < R;
  float r0[32], r1[32];

  // ---- load owned rows (cols c0..c0+31 are 16B aligned; c0 % 32 == 0) ----
  if (h0) {
    const float4* g = (const float4*)(A + (size_t)(c0 + s0) * N + c0);
    #pragma unroll
    for (int q = 0; q < 8; ++q) {
      float4 v = g[q];
      r0[4*q] = v.x; r0[4*q+1] = v.y; r0[4*q+2] = v.z; r0[4*q+3] = v.w;
    }
  }
  if (h1) {
    const float4* g = (const float4*)(A + (size_t)(c0 + s1) * N + c0);
    #pragma unroll
    for (int q = 0; q < 8; ++q) {
      float4 v = g[q];
      r1[4*q] = v.x; r1[4*q+1] = v.y; r1[4*q+2] = v.z; r1[4*q+3] = v.w;
    }
  }

  // ---- initial pivot scan, column 0 ----
  {
    float best = -1.0f; int bi = 0x7fffffff;
    if (h0) { float a = fabsf(r0[0]); if (a > best) { best = a; bi = s0; } }
    if (h1) { float a = fabsf(r1[0]); if (a > best) { best = a; bi = s1; } }
    wave_argmax(best, bi);
    if ((tid & 63) == 0) { redv[tid >> 6] = best; redi[tid >> 6] = bi; }
  }
  __syncthreads();
  int piv;
  {
    float bv = redv[0]; int b0 = redi[0];
    #pragma unroll
    for (int w = 1; w < 8; ++w)
      if (redv[w] > bv || (redv[w] == bv && redi[w] < b0)) { bv = redv[w]; b0 = redi[w]; }
    piv = b0;
  }
  if (tid == 0) ipiv[m * 32 + 0] = c0 + piv;

  double logsum = 0.0;
  #pragma unroll
  for (int j = 0; j < 32; ++j) {
    const int p = piv;   // uniform across threads (redundant combine)
    // ---- publish: owner(slot j) -> bufJ, owner(slot p) -> bufP ----
    if (s0 == j) {
      #pragma unroll
      for (int q = 0; q < 8; ++q)
        *(float4*)&bufJ[4*q] = make_float4(r0[4*q], r0[4*q+1], r0[4*q+2], r0[4*q+3]);
    }
    if (s1 == j) {
      #pragma unroll
      for (int q = 0; q < 8; ++q)
        *(float4*)&bufJ[4*q] = make_float4(r1[4*q], r1[4*q+1], r1[4*q+2], r1[4*q+3]);
    }
    if (s0 == p) {
      #pragma unroll
      for (int q = 0; q < 8; ++q)
        *(float4*)&bufP[4*q] = make_float4(r0[4*q], r0[4*q+1], r0[4*q+2], r0[4*q+3]);
    }
    if (s1 == p) {
      #pragma unroll
      for (int q = 0; q < 8; ++q)
        *(float4*)&bufP[4*q] = make_float4(r1[4*q], r1[4*q+1], r1[4*q+2], r1[4*q+3]);
    }
    __syncthreads();   // B1: bufJ/bufP visible; previous-iter redv reads done

    // ---- swap into registers: row j := bufP (pivot row); row p := bufJ ----
    if (s0 == j) {
      #pragma unroll
      for (int q = 0; q < 8; ++q) {
        float4 v = *(const float4*)&bufP[4*q];
        r0[4*q] = v.x; r0[4*q+1] = v.y; r0[4*q+2] = v.z; r0[4*q+3] = v.w;
      }
    }
    if (s1 == j) {
      #pragma unroll
      for (int q = 0; q < 8; ++q) {
        float4 v = *(const float4*)&bufP[4*q];
        r1[4*q] = v.x; r1[4*q+1] = v.y; r1[4*q+2] = v.z; r1[4*q+3] = v.w;
      }
    }
    if (p != j) {
      if (s0 == p) {
        #pragma unroll
        for (int q = 0; q < 8; ++q) {
          float4 v = *(const float4*)&bufJ[4*q];
          r0[4*q] = v.x; r0[4*q+1] = v.y; r0[4*q+2] = v.z; r0[4*q+3] = v.w;
        }
      }
      if (s1 == p) {
        #pragma unroll
        for (int q = 0; q < 8; ++q) {
          float4 v = *(const float4*)&bufJ[4*q];
          r1[4*q] = v.x; r1[4*q+1] = v.y; r1[4*q+2] = v.z; r1[4*q+3] = v.w;
        }
      }
    }

    const float ujj = bufP[j];
    if (tid == 0) logsum += log(fabs((double)ujj));
    const float rujj = 1.0f / ujj;

    // ---- scale L column + rank-1 update + fused scan of column j+1 ----
    const bool a0 = h0 && (s0 > j), a1 = h1 && (s1 > j);
    float l0 = 0.0f, l1 = 0.0f;
    if (a0) { l0 = r0[j] * rujj; r0[j] = l0; }
    if (a1) { l1 = r1[j] * rujj; r1[j] = l1; }

    if (j < 31) {
      float best = -1.0f; int bi = 0x7fffffff;
      {
        const float u = bufP[j + 1];
        if (a0) { float v = r0[j+1] - l0 * u; r0[j+1] = v; float a = fabsf(v); if (a > best) { best = a; bi = s0; } }
        if (a1) { float v = r1[j+1] - l1 * u; r1[j+1] = v; float a = fabsf(v); if (a > best) { best = a; bi = s1; } }
      }
      #pragma unroll
      for (int jj = j + 2; jj < 32; ++jj) {
        const float u = bufP[jj];
        if (a0) r0[jj] -= l0 * u;
        if (a1) r1[jj] -= l1 * u;
      }
      wave_argmax(best, bi);
      if ((tid & 63) == 0) { redv[tid >> 6] = best; redi[tid >> 6] = bi; }
    }
    __syncthreads();   // B2: redv complete; all bufJ/bufP reads of this iter done
    if (j < 31) {
      float bv = redv[0]; int b0 = redi[0];
      #pragma unroll
      for (int w = 1; w < 8; ++w)
        if (redv[w] > bv || (redv[w] == bv && redi[w] < b0)) { bv = redv[w]; b0 = redi[w]; }
      piv = b0;
      if (tid == 0) ipiv[m * 32 + j + 1] = c0 + b0;
    }
  }

  // ---- writeback owned rows ----
  if (h0) {
    float4* g = (float4*)(A + (size_t)(c0 + s0) * N + c0);
    #pragma unroll
    for (int q = 0; q < 8; ++q)
      g[q] = make_float4(r0[4*q], r0[4*q+1], r0[4*q+2], r0[4*q+3]);
  }
  if (h1) {
    float4* g = (float4*)(A + (size_t)(c0 + s1) * N + c0);
    #pragma unroll
    for (int q = 0; q < 8; ++q)
      g[q] = make_float4(r1[4*q], r1[4*q+1], r1[4*q+2], r1[4*q+3]);
  }
  if (tid == 0) atomicAdd(&scores[m], logsum);
}

// ======================= apply pivots to trailing cols + TRSM (U12 = L11^-1 A12) ===
// VERIFIED round-1/3 kernel, unchanged.
__global__ __launch_bounds__(256) void swap_trsm_kernel(float* __restrict__ lu,
                                                        const int* __restrict__ ipiv,
                                                        int c0, int cpb) {
  const int m  = blockIdx.x / cpb;
  const int cb = blockIdx.x % cpb;
  const int col = c0 + 32 + cb * 256 + threadIdx.x;
  float* A = lu + (size_t)m * NN;
  __shared__ float L[32][33];
  for (int idx = threadIdx.x; idx < 1024; idx += 256) {
    int i = idx >> 5, k = idx & 31;
    L[i][k] = A[(size_t)(c0 + i) * N + (c0 + k)];
  }
  __syncthreads();
  const bool act = col < N;
  #pragma unroll 1
  for (int j = 0; j < 32; ++j) {
    int p  = ipiv[m * 32 + j];
    int jg = c0 + j;
    if (p != jg && act) {
      float a = A[(size_t)jg * N + col];
      float b = A[(size_t)p  * N + col];
      A[(size_t)jg * N + col] = b;
      A[(size_t)p  * N + col] = a;
    }
  }
  if (act) {
    float u[32];
    #pragma unroll
    for (int i = 0; i < 32; ++i) {
      float a = A[(size_t)(c0 + i) * N + col];
      #pragma unroll
      for (int k = 0; k < 32; ++k)
        if (k < i) a -= L[i][k] * u[k];
      u[i] = a;
      A[(size_t)(c0 + i) * N + col] = a;
    }
  }
}

// ======================= trailing update: A22 -= L21 @ U12 (K=32) =======================
// VERIFIED round-1/3 kernel, unchanged.
__global__ __launch_bounds__(256) void gemm_update_kernel(float* __restrict__ lu, int c0, int nt) {
  const int m  = blockIdx.x / (nt * nt);
  const int t  = blockIdx.x % (nt * nt);
  const int tr = t / nt, tc = t % nt;
  const int r0  = c0 + 32 + tr * 64;
  const int cc0 = c0 + 32 + tc * 64;
  float* A = lu + (size_t)m * NN;
  __shared__ float Ls[64][33];
  __shared__ float Us[32][65];
  for (int idx = threadIdx.x; idx < 64 * 32; idx += 256) {
    int r = idx >> 5, k = idx & 31;
    Ls[r][k] = (r0 + r < N) ? A[(size_t)(r0 + r) * N + (c0 + k)] : 0.0f;
  }
  for (int idx = threadIdx.x; idx < 32 * 64; idx += 256) {
    int k = idx >> 6, c = idx & 63;
    Us[k][c] = (cc0 + c < N) ? A[(size_t)(c0 + k) * N + (cc0 + c)] : 0.0f;
  }
  __syncthreads();
  const int ty = threadIdx.x >> 4, tx = threadIdx.x & 15;
  float acc[4][4] = {};
  #pragma unroll
  for (int k = 0; k < 32; ++k) {
    float a[4], b[4];
    #pragma unroll
    for (int e = 0; e < 4; ++e) { a[e] = Ls[ty * 4 + e][k]; b[e] = Us[k][tx * 4 + e]; }
    #pragma unroll
    for (int i = 0; i < 4; ++i)
      #pragma unroll
      for (int jj = 0; jj < 4; ++jj) acc[i][jj] += a[i] * b[jj];
  }
  #pragma unroll
  for (int i = 0; i < 4; ++i) {
    int r = r0 + ty * 4 + i;
    if (r < N) {
      #pragma unroll
      for (int jj = 0; jj < 4; ++jj) {
        int c = cc0 + tx * 4 + jj;
        if (c < N) A[(size_t)r * N + c] -= acc[i][jj];
      }
    }
  }
}

// ======================= gate + top-k + effective weights =======================
__global__ void select_kernel(const void* __restrict__ flagsraw, const double* __restrict__ scores,
                              const float* __restrict__ w1, const float* __restrict__ b1,
                              const float* __restrict__ w2, const float* __restrict__ b2,
                              int* __restrict__ topidx, float* __restrict__ misc,
                              float* __restrict__ out_tail) {
  if (threadIdx.x != 0 || blockIdx.x != 0) return;
  const unsigned char* fb = (const unsigned char*)flagsraw;
  bool nonbin = false, off4 = false;
  for (int i = 0; i < 16; ++i) {
    if (fb[i] > 1) nonbin = true;
    if ((i & 3) && fb[i]) off4 = true;
  }
  int f[16]; int nact = 0;
  for (int i = 0; i < 16; ++i) {
    int v;
    if (nonbin)      v = (((const float*)flagsraw)[i] != 0.0f);
    else if (off4)   v = (fb[i] != 0);
    else             v = (((const int*)flagsraw)[i] != 0);
    f[i] = v; nact += v;
  }
  int gate = (nact >= 4) ? 1 : 0;   // THRESH = 4
  double sc[16];
  for (int i = 0; i < 16; ++i) sc[i] = f[i] ? scores[i] : -1.0e300;
  bool used[16] = {};
  for (int k = 0; k < 8; ++k) {     // descending, ties -> lowest index (lax.top_k)
    int bi = -1; double bv = 0.0;
    for (int i = 0; i < 16; ++i)
      if (!used[i] && (bi < 0 || sc[i] > bv)) { bv = sc[i]; bi = i; }
    used[bi] = true;
    topidx[k] = bi;
  }
  for (int cC = 0; cC < 10; ++cC) {
    float s = 0.0f;
    for (int h = 0; h < 32; ++h) s += w2[h] * w1[h * 10 + cC];
    misc[cC] = s;
  }
  float be = 0.0f;
  for (int h = 0; h < 32; ++h) be += w2[h] * b1[h];
  be += b2[0];
  misc[10] = be;
  ((int*)misc)[12] = gate;
  *out_tail = gate ? 1.0f : 0.0f;
}

// ======================= build combined right-hand matrices M0..M2 =======================
__global__ __launch_bounds__(256) void build_m_kernel(const float* __restrict__ x,
                                                      const int* __restrict__ topidx,
                                                      const float* __restrict__ misc,
                                                      float* __restrict__ M) {
  int i = blockIdx.x * 256 + threadIdx.x;   // 262144 float4 positions
  const float4* T1 = (const float4*)(x + (size_t)topidx[1] * NN);
  const float4* T2 = (const float4*)(x + (size_t)topidx[2] * NN);
  const float4* T3 = (const float4*)(x + (size_t)topidx[3] * NN);
  float w0 = misc[0], w1_ = misc[1], w2_ = misc[2], w3_ = misc[3], w4_ = misc[4], w5_ = misc[5];
  float4 t1 = T1[i], t2 = T2[i], t3 = T3[i];
  float4 m0, m1, m2;
  m0.x = w0 * t1.x + w1_ * t2.x + w2_ * t3.x;
  m0.y = w0 * t1.y + w1_ * t2.y + w2_ * t3.y;
  m0.z = w0 * t1.z + w1_ * t2.z + w2_ * t3.z;
  m0.w = w0 * t1.w + w1_ * t2.w + w2_ * t3.w;
  m1.x = w3_ * t2.x + w4_ * t3.x;
  m1.y = w3_ * t2.y + w4_ * t3.y;
  m1.z = w3_ * t2.z + w4_ * t3.z;
  m1.w = w3_ * t2.w + w4_ * t3.w;
  m2.x = w5_ * t3.x;  m2.y = w5_ * t3.y;  m2.z = w5_ * t3.z;  m2.w = w5_ * t3.w;
  ((float4*)M)[i] = m0;
  ((float4*)(M + NN))[i] = m1;
  ((float4*)(M + 2 * (size_t)NN))[i] = m2;
}

// ======================= split-K final GEMM: P[chunk] = A_chunk @ B_chunk ==========
// VERIFIED round-3 kernel, unchanged.
__global__ __launch_bounds__(256) void final_gemm_kernel(const float* __restrict__ x,
                                                         const float* __restrict__ M,
                                                         const int* __restrict__ topidx,
                                                         float* __restrict__ P) {
  const int chunk = blockIdx.x >> 8;   // 0..5
  const int t  = blockIdx.x & 255;
  const int tr = t >> 4, tc = t & 15;
  const int mi  = chunk >> 1;
  const int k0b = (chunk & 1) << 9;    // 0 or 512
  const float* A = x + (size_t)topidx[mi] * NN;
  const float* B = M + (size_t)mi * NN;
  __shared__ float As[32][68];   // A^T fragment: As[k][r], float4-aligned stride
  __shared__ float Bs[32][68];
  const int ty = threadIdx.x >> 4, tx = threadIdx.x & 15;
  float acc[4][4] = {};
  for (int k0 = k0b; k0 < k0b + 512; k0 += 32) {
    for (int idx = threadIdx.x; idx < 2048; idx += 256) {
      int r = idx >> 5, k = idx & 31;
      As[k][r] = A[(size_t)(tr * 64 + r) * N + k0 + k];
    }
    for (int idx = threadIdx.x; idx < 2048; idx += 256) {
      int k = idx >> 6, cc = idx & 63;
      Bs[k][cc] = B[(size_t)(k0 + k) * N + tc * 64 + cc];
    }
    __syncthreads();
    #pragma unroll 8
    for (int k = 0; k < 32; ++k) {
      float4 a = *(const float4*)&As[k][ty * 4];
      float4 b = *(const float4*)&Bs[k][tx * 4];
      acc[0][0] += a.x * b.x; acc[0][1] += a.x * b.y; acc[0][2] += a.x * b.z; acc[0][3] += a.x * b.w;
      acc[1][0] += a.y * b.x; acc[1][1] += a.y * b.y; acc[1][2] += a.y * b.z; acc[1][3] += a.y * b.w;
      acc[2][0] += a.z * b.x; acc[2][1] += a.z * b.y; acc[2][2] += a.z * b.z; acc[2][3] += a.z * b.w;
      acc[3][0] += a.w * b.x; acc[3][1] += a.w * b.y; acc[3][2] += a.w * b.z; acc[3][3] += a.w * b.w;
    }
    __syncthreads();
  }
  float* Pc = P + (size_t)chunk * NN;
  #pragma unroll
  for (int i = 0; i < 4; ++i) {
    size_t r = (size_t)(tr * 64 + ty * 4 + i);
    float4 v = make_float4(acc[i][0], acc[i][1], acc[i][2], acc[i][3]);
    *(float4*)&Pc[r * N + tc * 64 + tx * 4] = v;
  }
}

// ======================= reduce partials + preserve channels + bias ================
__global__ __launch_bounds__(256) void reduce_out_kernel(const float* __restrict__ x,
                                                         const float* __restrict__ P,
                                                         const int* __restrict__ topidx,
                                                         const float* __restrict__ misc,
                                                         float* __restrict__ out) {
  int i = blockIdx.x * 256 + threadIdx.x;   // 262144 float4 positions
  int gate = ((const int*)misc)[12];
  float4* o = (float4*)out;
  if (!gate) { o[i] = make_float4(0.f, 0.f, 0.f, 0.f); return; }
  float w6 = misc[6], w7 = misc[7], w8 = misc[8], w9 = misc[9], be = misc[10];
  float4 p0 = ((const float4*)(x + (size_t)topidx[4] * NN))[i];
  float4 p1 = ((const float4*)(x + (size_t)topidx[5] * NN))[i];
  float4 p2 = ((const float4*)(x + (size_t)topidx[6] * NN))[i];
  float4 p3 = ((const float4*)(x + (size_t)topidx[7] * NN))[i];
  float4 r;
  r.x = be + w6 * p0.x + w7 * p1.x + w8 * p2.x + w9 * p3.x;
  r.y = be + w6 * p0.y + w7 * p1.y + w8 * p2.y + w9 * p3.y;
  r.z = be + w6 * p0.z + w7 * p1.z + w8 * p2.z + w9 * p3.z;
  r.w = be + w6 * p0.w + w7 * p1.w + w8 * p2.w + w9 * p3.w;
  #pragma unroll
  for (int cN = 0; cN < 6; ++cN) {
    float4 q = ((const float4*)(P + (size_t)cN * NN))[i];
    r.x += q.x; r.y += q.y; r.z += q.z; r.w += q.w;
  }
  o[i] = r;
}

// ======================= host =======================
extern "C" void kernel_launch(void* const* d_in, const int* in_sizes, int n_in,
                              void* d_out, int out_size, void* d_ws, size_t ws_size,
                              hipStream_t stream) {
  const float* x  = (const float*)d_in[0];
  const void*  fl = d_in[1];
  const float* w1 = (const float*)d_in[2];
  const float* b1 = (const float*)d_in[3];
  const float* w2 = (const float*)d_in[4];
  const float* b2 = (const float*)d_in[5];
  float* out = (float*)d_out;

  char* ws = (char*)d_ws;
  float* LU = (float*)ws;                                // 64 MB (dead after LU phase)
  float* Mm = (float*)ws;                                // 12 MB, reuses LU space
  float* P  = (float*)(ws + (size_t)12 * 1024 * 1024);   // 24 MB partials, inside old LU
  size_t tail = (size_t)16 * NN * sizeof(float);         // 67,108,864
  double* scores = (double*)(ws + tail);                 // 16 doubles
  int*    ipiv   = (int*)(ws + tail + 256);              // 16*32 ints
  int*    topidx = (int*)(ws + tail + 256 + 2304);       // 8 ints
  float*  misc   = (float*)(ws + tail + 256 + 2304 + 256); // weff[10], beff, gate

  init_kernel<<<1, 64, 0, stream>>>(scores);
  copy_kernel<<<16384, 256, 0, stream>>>((const float4*)x, (float4*)LU);

  for (int c0 = 0; c0 < N; c0 += 32) {
    panel_kernel<<<16, 512, 0, stream>>>(LU, ipiv, scores, c0);
    int tcols = N - c0 - 32;
    if (tcols > 0) {
      int cpb = (tcols + 255) / 256;
      swap_trsm_kernel<<<16 * cpb, 256, 0, stream>>>(LU, ipiv, c0, cpb);
      int nt = (tcols + 63) / 64;
      gemm_update_kernel<<<16 * nt * nt, 256, 0, stream>>>(LU, c0, nt);
    }
  }

  select_kernel<<<1, 64, 0, stream>>>(fl, scores, w1, b1, w2, b2, topidx, misc, out + NN);
  build_m_kernel<<<1024, 256, 0, stream>>>(x, topidx, misc, Mm);
  final_gemm_kernel<<<1536, 256, 0, stream>>>(x, Mm, topidx, P);
  reduce_out_kernel<<<1024, 256, 0, stream>>>(x, P, topidx, misc, out);
}

// Round 5
// 5331.384 us; speedup vs baseline: 2.0930x; 2.0930x over previous
//
#include <hip/hip_runtime.h>
#include <math.h>

#define N 1024
#define NN (N*N)

// ---------- wave argmax over (val, key): max val, tie -> min key ----------
__device__ __forceinline__ void wave_argmax_kv(float& v, int& k) {
  #pragma unroll
  for (int off = 32; off > 0; off >>= 1) {
    float ov = __shfl_down(v, off);
    int   ok = __shfl_down(k, off);
    if (ov > v || (ov == v && ok < k)) { v = ov; k = ok; }
  }
}

// ======================= init =======================
__global__ void init_kernel(double* scores) {
  int t = threadIdx.x;
  if (t < 16) scores[t] = 0.0;
}

// ======================= copy x -> LU workspace =======================
__global__ __launch_bounds__(256) void copy_kernel(const float4* __restrict__ src,
                                                   float4* __restrict__ dst) {
  int i = blockIdx.x * 256 + threadIdx.x;   // grid sized exactly: 16M floats / 4
  dst[i] = src[i];
}

// ======================= LU panel (width 32): no-swap register-resident =========
// 1024 threads/block, one block per matrix. Thread t owns panel-local row t
// (32 floats) in registers PERMANENTLY — rows never move between threads
// (R4's conditional register swap caused scratch spill; deleted). The pivot
// row retires in place: publishes to LDS bufP, flips active=false. LAPACK
// layout is reconstructed via a position simulation (lay/posOf, 2 LDS writes
// per step by thread 0); ipiv and writeback positions are exactly LAPACK's,
// tie-break = lowest current position via key=(pos<<11)|orig. Per-element fp
// ops identical to the verified R3 panel -> bitwise-same LU and scores.
// 2 barriers/step; next-column pivot scan fused into the rank-1 update
// (concept correctness-verified in R4).
__global__ __launch_bounds__(1024) void panel_kernel(float* __restrict__ lu,
                                                     int* __restrict__ ipiv,
                                                     double* __restrict__ scores,
                                                     int c0) {
  __shared__ __align__(16) float bufP[32];
  __shared__ float ujjS[32];
  __shared__ float redv[16];
  __shared__ int   redk[16];
  __shared__ int   posOf[1024];
  __shared__ int   lay[1024];
  const int m = blockIdx.x;
  float* A = lu + (size_t)m * NN;
  const int R = N - c0;
  const int tid = threadIdx.x;
  bool active = tid < R;
  float row[32];

  if (active) {   // cols c0..c0+31 are 16B-aligned (c0 % 32 == 0)
    const float4* g = (const float4*)(A + (size_t)(c0 + tid) * N + c0);
    #pragma unroll
    for (int q = 0; q < 8; ++q) {
      float4 v = g[q];
      row[4*q] = v.x; row[4*q+1] = v.y; row[4*q+2] = v.z; row[4*q+3] = v.w;
    }
  }
  posOf[tid] = tid;
  lay[tid]   = tid;
  __syncthreads();

  // ---- pre-scan: pivot for column 0 ----
  int worig;
  {
    float val = active ? fabsf(row[0]) : -1.0f;
    int key = (tid << 11) | tid;   // pos = tid initially
    wave_argmax_kv(val, key);
    if ((tid & 63) == 0) { redv[tid >> 6] = val; redk[tid >> 6] = key; }
    __syncthreads();
    float bv = redv[0]; int bk = redk[0];
    #pragma unroll 1
    for (int w = 1; w < 16; ++w)
      if (redv[w] > bv || (redv[w] == bv && redk[w] < bk)) { bv = redv[w]; bk = redk[w]; }
    worig = bk & 0x7FF;
  }

  #pragma unroll
  for (int j = 0; j < 32; ++j) {
    if (tid == worig) {   // publish pivot row, retire in place
      #pragma unroll
      for (int q = 0; q < 8; ++q)
        *(float4*)&bufP[4*q] = make_float4(row[4*q], row[4*q+1], row[4*q+2], row[4*q+3]);
      active = false;
    }
    if (tid == 0) {       // LAPACK swap simulation (positions only)
      int p = posOf[worig];
      ipiv[m * 32 + j] = c0 + p;
      int a = lay[j];
      lay[j] = worig; lay[p] = a;
      posOf[worig] = j; posOf[a] = p;
    }
    __syncthreads();      // B1: bufP + posOf(step j) visible

    // U-row j into registers (only quads covering cols >= j)
    float u[32];
    #pragma unroll
    for (int q = 0; q < 8; ++q) {
      if (4*q + 3 >= j) {
        float4 v = *(const float4*)&bufP[4*q];
        u[4*q] = v.x; u[4*q+1] = v.y; u[4*q+2] = v.z; u[4*q+3] = v.w;
      }
    }
    if (tid == 0) ujjS[j] = u[j];
    const float rujj = 1.0f / u[j];

    float l = 0.0f;
    if (active) { l = row[j] * rujj; row[j] = l; }

    float val = -1.0f; int key = 0x7fffffff;
    if (j < 31) {
      if (active) {
        float v = row[j+1] - l * u[j+1];   // peeled col j+1: update + scan
        row[j+1] = v;
        #pragma unroll
        for (int jj = j + 2; jj < 32; ++jj) row[jj] -= l * u[jj];
        int mypos = posOf[tid];
        val = fabsf(v); key = (mypos << 11) | tid;
      }
      wave_argmax_kv(val, key);
      if ((tid & 63) == 0) { redv[tid >> 6] = val; redk[tid >> 6] = key; }
    }
    __syncthreads();      // B2: redv/redk complete; bufP/posOf reads done
    if (j < 31) {
      float bv = redv[0]; int bk = redk[0];
      #pragma unroll 1
      for (int w = 1; w < 16; ++w)
        if (redv[w] > bv || (redv[w] == bv && redk[w] < bk)) { bv = redv[w]; bk = redk[w]; }
      worig = bk & 0x7FF;
    }
  }

  // ---- writeback: each row to its final LAPACK position ----
  if (tid < R) {
    int fp = posOf[tid];
    float4* g = (float4*)(A + (size_t)(c0 + fp) * N + c0);
    #pragma unroll
    for (int q = 0; q < 8; ++q)
      g[q] = make_float4(row[4*q], row[4*q+1], row[4*q+2], row[4*q+3]);
  }
  if (tid == 0) {
    double logsum = 0.0;
    #pragma unroll 1
    for (int j = 0; j < 32; ++j) logsum += log(fabs((double)ujjS[j]));
    atomicAdd(&scores[m], logsum);
  }
}

// ======================= apply pivots to trailing cols + TRSM (U12 = L11^-1 A12) ===
// VERIFIED round-1/3 kernel, unchanged.
__global__ __launch_bounds__(256) void swap_trsm_kernel(float* __restrict__ lu,
                                                        const int* __restrict__ ipiv,
                                                        int c0, int cpb) {
  const int m  = blockIdx.x / cpb;
  const int cb = blockIdx.x % cpb;
  const int col = c0 + 32 + cb * 256 + threadIdx.x;
  float* A = lu + (size_t)m * NN;
  __shared__ float L[32][33];
  for (int idx = threadIdx.x; idx < 1024; idx += 256) {
    int i = idx >> 5, k = idx & 31;
    L[i][k] = A[(size_t)(c0 + i) * N + (c0 + k)];
  }
  __syncthreads();
  const bool act = col < N;
  #pragma unroll 1
  for (int j = 0; j < 32; ++j) {
    int p  = ipiv[m * 32 + j];
    int jg = c0 + j;
    if (p != jg && act) {
      float a = A[(size_t)jg * N + col];
      float b = A[(size_t)p  * N + col];
      A[(size_t)jg * N + col] = b;
      A[(size_t)p  * N + col] = a;
    }
  }
  if (act) {
    float u[32];
    #pragma unroll
    for (int i = 0; i < 32; ++i) {
      float a = A[(size_t)(c0 + i) * N + col];
      #pragma unroll
      for (int k = 0; k < 32; ++k)
        if (k < i) a -= L[i][k] * u[k];
      u[i] = a;
      A[(size_t)(c0 + i) * N + col] = a;
    }
  }
}

// ======================= trailing update: A22 -= L21 @ U12 (K=32) =======================
// VERIFIED round-1/3 kernel, unchanged.
__global__ __launch_bounds__(256) void gemm_update_kernel(float* __restrict__ lu, int c0, int nt) {
  const int m  = blockIdx.x / (nt * nt);
  const int t  = blockIdx.x % (nt * nt);
  const int tr = t / nt, tc = t % nt;
  const int r0  = c0 + 32 + tr * 64;
  const int cc0 = c0 + 32 + tc * 64;
  float* A = lu + (size_t)m * NN;
  __shared__ float Ls[64][33];
  __shared__ float Us[32][65];
  for (int idx = threadIdx.x; idx < 64 * 32; idx += 256) {
    int r = idx >> 5, k = idx & 31;
    Ls[r][k] = (r0 + r < N) ? A[(size_t)(r0 + r) * N + (c0 + k)] : 0.0f;
  }
  for (int idx = threadIdx.x; idx < 32 * 64; idx += 256) {
    int k = idx >> 6, c = idx & 63;
    Us[k][c] = (cc0 + c < N) ? A[(size_t)(c0 + k) * N + (cc0 + c)] : 0.0f;
  }
  __syncthreads();
  const int ty = threadIdx.x >> 4, tx = threadIdx.x & 15;
  float acc[4][4] = {};
  #pragma unroll
  for (int k = 0; k < 32; ++k) {
    float a[4], b[4];
    #pragma unroll
    for (int e = 0; e < 4; ++e) { a[e] = Ls[ty * 4 + e][k]; b[e] = Us[k][tx * 4 + e]; }
    #pragma unroll
    for (int i = 0; i < 4; ++i)
      #pragma unroll
      for (int jj = 0; jj < 4; ++jj) acc[i][jj] += a[i] * b[jj];
  }
  #pragma unroll
  for (int i = 0; i < 4; ++i) {
    int r = r0 + ty * 4 + i;
    if (r < N) {
      #pragma unroll
      for (int jj = 0; jj < 4; ++jj) {
        int c = cc0 + tx * 4 + jj;
        if (c < N) A[(size_t)r * N + c] -= acc[i][jj];
      }
    }
  }
}

// ======================= gate + top-k + effective weights =======================
__global__ void select_kernel(const void* __restrict__ flagsraw, const double* __restrict__ scores,
                              const float* __restrict__ w1, const float* __restrict__ b1,
                              const float* __restrict__ w2, const float* __restrict__ b2,
                              int* __restrict__ topidx, float* __restrict__ misc,
                              float* __restrict__ out_tail) {
  if (threadIdx.x != 0 || blockIdx.x != 0) return;
  const unsigned char* fb = (const unsigned char*)flagsraw;
  bool nonbin = false, off4 = false;
  for (int i = 0; i < 16; ++i) {
    if (fb[i] > 1) nonbin = true;
    if ((i & 3) && fb[i]) off4 = true;
  }
  int f[16]; int nact = 0;
  for (int i = 0; i < 16; ++i) {
    int v;
    if (nonbin)      v = (((const float*)flagsraw)[i] != 0.0f);
    else if (off4)   v = (fb[i] != 0);
    else             v = (((const int*)flagsraw)[i] != 0);
    f[i] = v; nact += v;
  }
  int gate = (nact >= 4) ? 1 : 0;   // THRESH = 4
  double sc[16];
  for (int i = 0; i < 16; ++i) sc[i] = f[i] ? scores[i] : -1.0e300;
  bool used[16] = {};
  for (int k = 0; k < 8; ++k) {     // descending, ties -> lowest index (lax.top_k)
    int bi = -1; double bv = 0.0;
    for (int i = 0; i < 16; ++i)
      if (!used[i] && (bi < 0 || sc[i] > bv)) { bv = sc[i]; bi = i; }
    used[bi] = true;
    topidx[k] = bi;
  }
  for (int cC = 0; cC < 10; ++cC) {
    float s = 0.0f;
    for (int h = 0; h < 32; ++h) s += w2[h] * w1[h * 10 + cC];
    misc[cC] = s;
  }
  float be = 0.0f;
  for (int h = 0; h < 32; ++h) be += w2[h] * b1[h];
  be += b2[0];
  misc[10] = be;
  ((int*)misc)[12] = gate;
  *out_tail = gate ? 1.0f : 0.0f;
}

// ======================= build combined right-hand matrices M0..M2 =======================
__global__ __launch_bounds__(256) void build_m_kernel(const float* __restrict__ x,
                                                      const int* __restrict__ topidx,
                                                      const float* __restrict__ misc,
                                                      float* __restrict__ M) {
  int i = blockIdx.x * 256 + threadIdx.x;   // 262144 float4 positions
  const float4* T1 = (const float4*)(x + (size_t)topidx[1] * NN);
  const float4* T2 = (const float4*)(x + (size_t)topidx[2] * NN);
  const float4* T3 = (const float4*)(x + (size_t)topidx[3] * NN);
  float w0 = misc[0], w1_ = misc[1], w2_ = misc[2], w3_ = misc[3], w4_ = misc[4], w5_ = misc[5];
  float4 t1 = T1[i], t2 = T2[i], t3 = T3[i];
  float4 m0, m1, m2;
  m0.x = w0 * t1.x + w1_ * t2.x + w2_ * t3.x;
  m0.y = w0 * t1.y + w1_ * t2.y + w2_ * t3.y;
  m0.z = w0 * t1.z + w1_ * t2.z + w2_ * t3.z;
  m0.w = w0 * t1.w + w1_ * t2.w + w2_ * t3.w;
  m1.x = w3_ * t2.x + w4_ * t3.x;
  m1.y = w3_ * t2.y + w4_ * t3.y;
  m1.z = w3_ * t2.z + w4_ * t3.z;
  m1.w = w3_ * t2.w + w4_ * t3.w;
  m2.x = w5_ * t3.x;  m2.y = w5_ * t3.y;  m2.z = w5_ * t3.z;  m2.w = w5_ * t3.w;
  ((float4*)M)[i] = m0;
  ((float4*)(M + NN))[i] = m1;
  ((float4*)(M + 2 * (size_t)NN))[i] = m2;
}

// ======================= split-K final GEMM: P[chunk] = A_chunk @ B_chunk ==========
// VERIFIED round-3 kernel, unchanged.
__global__ __launch_bounds__(256) void final_gemm_kernel(const float* __restrict__ x,
                                                         const float* __restrict__ M,
                                                         const int* __restrict__ topidx,
                                                         float* __restrict__ P) {
  const int chunk = blockIdx.x >> 8;   // 0..5
  const int t  = blockIdx.x & 255;
  const int tr = t >> 4, tc = t & 15;
  const int mi  = chunk >> 1;
  const int k0b = (chunk & 1) << 9;    // 0 or 512
  const float* A = x + (size_t)topidx[mi] * NN;
  const float* B = M + (size_t)mi * NN;
  __shared__ float As[32][68];   // A^T fragment: As[k][r], float4-aligned stride
  __shared__ float Bs[32][68];
  const int ty = threadIdx.x >> 4, tx = threadIdx.x & 15;
  float acc[4][4] = {};
  for (int k0 = k0b; k0 < k0b + 512; k0 += 32) {
    for (int idx = threadIdx.x; idx < 2048; idx += 256) {
      int r = idx >> 5, k = idx & 31;
      As[k][r] = A[(size_t)(tr * 64 + r) * N + k0 + k];
    }
    for (int idx = threadIdx.x; idx < 2048; idx += 256) {
      int k = idx >> 6, cc = idx & 63;
      Bs[k][cc] = B[(size_t)(k0 + k) * N + tc * 64 + cc];
    }
    __syncthreads();
    #pragma unroll 8
    for (int k = 0; k < 32; ++k) {
      float4 a = *(const float4*)&As[k][ty * 4];
      float4 b = *(const float4*)&Bs[k][tx * 4];
      acc[0][0] += a.x * b.x; acc[0][1] += a.x * b.y; acc[0][2] += a.x * b.z; acc[0][3] += a.x * b.w;
      acc[1][0] += a.y * b.x; acc[1][1] += a.y * b.y; acc[1][2] += a.y * b.z; acc[1][3] += a.y * b.w;
      acc[2][0] += a.z * b.x; acc[2][1] += a.z * b.y; acc[2][2] += a.z * b.z; acc[2][3] += a.z * b.w;
      acc[3][0] += a.w * b.x; acc[3][1] += a.w * b.y; acc[3][2] += a.w * b.z; acc[3][3] += a.w * b.w;
    }
    __syncthreads();
  }
  float* Pc = P + (size_t)chunk * NN;
  #pragma unroll
  for (int i = 0; i < 4; ++i) {
    size_t r = (size_t)(tr * 64 + ty * 4 + i);
    float4 v = make_float4(acc[i][0], acc[i][1], acc[i][2], acc[i][3]);
    *(float4*)&Pc[r * N + tc * 64 + tx * 4] = v;
  }
}

// ======================= reduce partials + preserve channels + bias ================
__global__ __launch_bounds__(256) void reduce_out_kernel(const float* __restrict__ x,
                                                         const float* __restrict__ P,
                                                         const int* __restrict__ topidx,
                                                         const float* __restrict__ misc,
                                                         float* __restrict__ out) {
  int i = blockIdx.x * 256 + threadIdx.x;   // 262144 float4 positions
  int gate = ((const int*)misc)[12];
  float4* o = (float4*)out;
  if (!gate) { o[i] = make_float4(0.f, 0.f, 0.f, 0.f); return; }
  float w6 = misc[6], w7 = misc[7], w8 = misc[8], w9 = misc[9], be = misc[10];
  float4 p0 = ((const float4*)(x + (size_t)topidx[4] * NN))[i];
  float4 p1 = ((const float4*)(x + (size_t)topidx[5] * NN))[i];
  float4 p2 = ((const float4*)(x + (size_t)topidx[6] * NN))[i];
  float4 p3 = ((const float4*)(x + (size_t)topidx[7] * NN))[i];
  float4 r;
  r.x = be + w6 * p0.x + w7 * p1.x + w8 * p2.x + w9 * p3.x;
  r.y = be + w6 * p0.y + w7 * p1.y + w8 * p2.y + w9 * p3.y;
  r.z = be + w6 * p0.z + w7 * p1.z + w8 * p2.z + w9 * p3.z;
  r.w = be + w6 * p0.w + w7 * p1.w + w8 * p2.w + w9 * p3.w;
  #pragma unroll
  for (int cN = 0; cN < 6; ++cN) {
    float4 q = ((const float4*)(P + (size_t)cN * NN))[i];
    r.x += q.x; r.y += q.y; r.z += q.z; r.w += q.w;
  }
  o[i] = r;
}

// ======================= host =======================
extern "C" void kernel_launch(void* const* d_in, const int* in_sizes, int n_in,
                              void* d_out, int out_size, void* d_ws, size_t ws_size,
                              hipStream_t stream) {
  const float* x  = (const float*)d_in[0];
  const void*  fl = d_in[1];
  const float* w1 = (const float*)d_in[2];
  const float* b1 = (const float*)d_in[3];
  const float* w2 = (const float*)d_in[4];
  const float* b2 = (const float*)d_in[5];
  float* out = (float*)d_out;

  char* ws = (char*)d_ws;
  float* LU = (float*)ws;                                // 64 MB (dead after LU phase)
  float* Mm = (float*)ws;                                // 12 MB, reuses LU space
  float* P  = (float*)(ws + (size_t)12 * 1024 * 1024);   // 24 MB partials, inside old LU
  size_t tail = (size_t)16 * NN * sizeof(float);         // 67,108,864
  double* scores = (double*)(ws + tail);                 // 16 doubles
  int*    ipiv   = (int*)(ws + tail + 256);              // 16*32 ints
  int*    topidx = (int*)(ws + tail + 256 + 2304);       // 8 ints
  float*  misc   = (float*)(ws + tail + 256 + 2304 + 256); // weff[10], beff, gate

  init_kernel<<<1, 64, 0, stream>>>(scores);
  copy_kernel<<<16384, 256, 0, stream>>>((const float4*)x, (float4*)LU);

  for (int c0 = 0; c0 < N; c0 += 32) {
    panel_kernel<<<16, 1024, 0, stream>>>(LU, ipiv, scores, c0);
    int tcols = N - c0 - 32;
    if (tcols > 0) {
      int cpb = (tcols + 255) / 256;
      swap_trsm_kernel<<<16 * cpb, 256, 0, stream>>>(LU, ipiv, c0, cpb);
      int nt = (tcols + 63) / 64;
      gemm_update_kernel<<<16 * nt * nt, 256, 0, stream>>>(LU, c0, nt);
    }
  }

  select_kernel<<<1, 64, 0, stream>>>(fl, scores, w1, b1, w2, b2, topidx, misc, out + NN);
  build_m_kernel<<<1024, 256, 0, stream>>>(x, topidx, misc, Mm);
  final_gemm_kernel<<<1536, 256, 0, stream>>>(x, Mm, topidx, P);
  reduce_out_kernel<<<1024, 256, 0, stream>>>(x, P, topidx, misc, out);
}

// Round 6
// 5150.856 us; speedup vs baseline: 2.1664x; 1.0350x over previous
//
#include <hip/hip_runtime.h>
#include <math.h>

#define N 1024
#define NN (N*N)

// ---------- wave argmax over (val, key): max val, tie -> min key ----------
__device__ __forceinline__ void wave_argmax_kv(float& v, int& k) {
  #pragma unroll
  for (int off = 32; off > 0; off >>= 1) {
    float ov = __shfl_down(v, off);
    int   ok = __shfl_down(k, off);
    if (ov > v || (ov == v && ok < k)) { v = ov; k = ok; }
  }
}

// ======================= init =======================
__global__ void init_kernel(double* scores) {
  int t = threadIdx.x;
  if (t < 16) scores[t] = 0.0;
}

// ======================= copy x -> LU workspace =======================
__global__ __launch_bounds__(256) void copy_kernel(const float4* __restrict__ src,
                                                   float4* __restrict__ dst) {
  int i = blockIdx.x * 256 + threadIdx.x;   // grid sized exactly: 16M floats / 4
  dst[i] = src[i];
}

// ======================= LU panel (width 32): no-swap register-resident =========
// VERIFIED round-5 kernel, unchanged.
__global__ __launch_bounds__(1024) void panel_kernel(float* __restrict__ lu,
                                                     int* __restrict__ ipiv,
                                                     double* __restrict__ scores,
                                                     int c0) {
  __shared__ __align__(16) float bufP[32];
  __shared__ float ujjS[32];
  __shared__ float redv[16];
  __shared__ int   redk[16];
  __shared__ int   posOf[1024];
  __shared__ int   lay[1024];
  const int m = blockIdx.x;
  float* A = lu + (size_t)m * NN;
  const int R = N - c0;
  const int tid = threadIdx.x;
  bool active = tid < R;
  float row[32];

  if (active) {   // cols c0..c0+31 are 16B-aligned (c0 % 32 == 0)
    const float4* g = (const float4*)(A + (size_t)(c0 + tid) * N + c0);
    #pragma unroll
    for (int q = 0; q < 8; ++q) {
      float4 v = g[q];
      row[4*q] = v.x; row[4*q+1] = v.y; row[4*q+2] = v.z; row[4*q+3] = v.w;
    }
  }
  posOf[tid] = tid;
  lay[tid]   = tid;
  __syncthreads();

  // ---- pre-scan: pivot for column 0 ----
  int worig;
  {
    float val = active ? fabsf(row[0]) : -1.0f;
    int key = (tid << 11) | tid;   // pos = tid initially
    wave_argmax_kv(val, key);
    if ((tid & 63) == 0) { redv[tid >> 6] = val; redk[tid >> 6] = key; }
    __syncthreads();
    float bv = redv[0]; int bk = redk[0];
    #pragma unroll 1
    for (int w = 1; w < 16; ++w)
      if (redv[w] > bv || (redv[w] == bv && redk[w] < bk)) { bv = redv[w]; bk = redk[w]; }
    worig = bk & 0x7FF;
  }

  #pragma unroll
  for (int j = 0; j < 32; ++j) {
    if (tid == worig) {   // publish pivot row, retire in place
      #pragma unroll
      for (int q = 0; q < 8; ++q)
        *(float4*)&bufP[4*q] = make_float4(row[4*q], row[4*q+1], row[4*q+2], row[4*q+3]);
      active = false;
    }
    if (tid == 0) {       // LAPACK swap simulation (positions only)
      int p = posOf[worig];
      ipiv[m * 32 + j] = c0 + p;
      int a = lay[j];
      lay[j] = worig; lay[p] = a;
      posOf[worig] = j; posOf[a] = p;
    }
    __syncthreads();      // B1: bufP + posOf(step j) visible

    // U-row j into registers (only quads covering cols >= j)
    float u[32];
    #pragma unroll
    for (int q = 0; q < 8; ++q) {
      if (4*q + 3 >= j) {
        float4 v = *(const float4*)&bufP[4*q];
        u[4*q] = v.x; u[4*q+1] = v.y; u[4*q+2] = v.z; u[4*q+3] = v.w;
      }
    }
    if (tid == 0) ujjS[j] = u[j];
    const float rujj = 1.0f / u[j];

    float l = 0.0f;
    if (active) { l = row[j] * rujj; row[j] = l; }

    float val = -1.0f; int key = 0x7fffffff;
    if (j < 31) {
      if (active) {
        float v = row[j+1] - l * u[j+1];   // peeled col j+1: update + scan
        row[j+1] = v;
        #pragma unroll
        for (int jj = j + 2; jj < 32; ++jj) row[jj] -= l * u[jj];
        int mypos = posOf[tid];
        val = fabsf(v); key = (mypos << 11) | tid;
      }
      wave_argmax_kv(val, key);
      if ((tid & 63) == 0) { redv[tid >> 6] = val; redk[tid >> 6] = key; }
    }
    __syncthreads();      // B2: redv/redk complete; bufP/posOf reads done
    if (j < 31) {
      float bv = redv[0]; int bk = redk[0];
      #pragma unroll 1
      for (int w = 1; w < 16; ++w)
        if (redv[w] > bv || (redv[w] == bv && redk[w] < bk)) { bv = redv[w]; bk = redk[w]; }
      worig = bk & 0x7FF;
    }
  }

  // ---- writeback: each row to its final LAPACK position ----
  if (tid < R) {
    int fp = posOf[tid];
    float4* g = (float4*)(A + (size_t)(c0 + fp) * N + c0);
    #pragma unroll
    for (int q = 0; q < 8; ++q)
      g[q] = make_float4(row[4*q], row[4*q+1], row[4*q+2], row[4*q+3]);
  }
  if (tid == 0) {
    double logsum = 0.0;
    #pragma unroll 1
    for (int j = 0; j < 32; ++j) logsum += log(fabs((double)ujjS[j]));
    atomicAdd(&scores[m], logsum);
  }
}

// ======================= permutation-gather + TRSM (replaces swap_trsm) ==========
// One block per 256-col stripe of the trailing matrix. thread0 simulates the 32
// sequential row swaps on an LDS rowAt[] map; then each thread (one column):
// reads the <=32 displaced-row payloads and the 32 A12 sources into registers
// (gather), solves U12 = L11^{-1} A12, and only then writes displaced rows +
// U12. Final global state provably identical to the old sequential-swap kernel;
// columns are thread-private so there are no cross-thread hazards.
__global__ __launch_bounds__(256) void ptrsm_kernel(float* __restrict__ lu,
                                                    const int* __restrict__ ipiv,
                                                    int c0, int ncs) {
  const int m  = blockIdx.x / ncs;
  const int cs = blockIdx.x % ncs;
  const int s0 = c0 + 32 + cs * 256;
  const int tid = threadIdx.x;
  const int col = s0 + tid;
  const bool ac = col < N;
  float* A = lu + (size_t)m * NN;
  const int R = N - c0;
  __shared__ int   rowAt[1024];     // content map over rows [c0, N)
  __shared__ float L11s[32][33];
  __shared__ int   dDst[48];
  __shared__ int   dSrc[48];
  __shared__ int   dcount;

  for (int r = tid; r < R; r += 256) rowAt[r] = c0 + r;
  if (tid == 0) dcount = 0;
  for (int idx = tid; idx < 1024; idx += 256) {
    int i = idx >> 5, k = idx & 31;
    L11s[i][k] = A[(size_t)(c0 + i) * N + c0 + k];
  }
  __syncthreads();
  if (tid == 0) {
    #pragma unroll 1
    for (int j = 0; j < 32; ++j) {
      int p = ipiv[m * 32 + j];
      if (p != c0 + j) { int t = rowAt[j]; rowAt[j] = rowAt[p - c0]; rowAt[p - c0] = t; }
    }
  }
  __syncthreads();
  // collect displaced A22 rows (dst receives content of src)
  for (int r = 32 + tid; r < R; r += 256) {
    if (rowAt[r] != c0 + r) {
      int i = atomicAdd(&dcount, 1);
      dDst[i] = c0 + r; dSrc[i] = rowAt[r];
    }
  }
  __syncthreads();
  const int nd = dcount;   // <= 32

  // ---- read phase (all loads before any store) ----
  float pay[32];
  #pragma unroll
  for (int i = 0; i < 32; ++i)
    if (i < nd && ac) pay[i] = A[(size_t)dSrc[i] * N + col];
  float u[32];
  #pragma unroll
  for (int i = 0; i < 32; ++i)
    if (ac) u[i] = A[(size_t)rowAt[i] * N + col];

  // ---- TRSM: u = L11^{-1} a12 (unit diag) ----
  #pragma unroll
  for (int i = 1; i < 32; ++i) {
    float a = u[i];
    #pragma unroll
    for (int k = 0; k < 32; ++k)
      if (k < i) a -= L11s[i][k] * u[k];
    u[i] = a;
  }

  // ---- write phase ----
  #pragma unroll
  for (int i = 0; i < 32; ++i)
    if (i < nd && ac) A[(size_t)dDst[i] * N + col] = pay[i];
  #pragma unroll
  for (int i = 0; i < 32; ++i)
    if (ac) A[(size_t)(c0 + i) * N + col] = u[i];
}

// ======================= trailing update: A22 -= L21 @ U12 (K=32) ================
// 64-row x 256-col tiles: A22 read-modify-write in contiguous 1KB row bursts.
// LDS: Us[k][c] (b128 reads at 16B stride over 64 lanes = 2-way, free) and
// transposed Lts[k][r] (b128 reads wave-uniform = broadcast, free).
__global__ __launch_bounds__(256) void update_kernel(float* __restrict__ lu,
                                                     int c0, int nrt, int ncs) {
  const int per = nrt * ncs;
  const int m  = blockIdx.x / per;
  const int t  = blockIdx.x % per;
  const int rt = t / ncs, cs = t % ncs;
  const int r0 = c0 + 32 + rt * 64;
  const int s0 = c0 + 32 + cs * 256;
  const int tid = threadIdx.x;
  float* A = lu + (size_t)m * NN;
  __shared__ float Lts[32][68];    // L21 tile transposed: [k][r]
  __shared__ float Us[32][260];    // U12 stripe: [k][c]
  for (int idx = tid; idx < 2048; idx += 256) {
    int r = idx >> 5, k = idx & 31;
    Lts[k][r] = (r0 + r < N) ? A[(size_t)(r0 + r) * N + c0 + k] : 0.0f;
  }
  for (int idx = tid; idx < 8192; idx += 256) {
    int k = idx >> 8, c = idx & 255;
    Us[k][c] = (s0 + c < N) ? A[(size_t)(c0 + k) * N + s0 + c] : 0.0f;
  }
  __syncthreads();
  const int tx = tid & 63;    // col group: 4 cols
  const int ty = tid >> 6;    // row group: 16 rows (== wave id -> uniform a-reads)
  float4 acc[16];
  #pragma unroll
  for (int e = 0; e < 16; ++e) acc[e] = make_float4(0.f, 0.f, 0.f, 0.f);
  #pragma unroll 4
  for (int k = 0; k < 32; ++k) {
    float4 b  = *(const float4*)&Us[k][tx * 4];
    float4 a0 = *(const float4*)&Lts[k][ty * 16 + 0];
    float4 a1 = *(const float4*)&Lts[k][ty * 16 + 4];
    float4 a2 = *(const float4*)&Lts[k][ty * 16 + 8];
    float4 a3 = *(const float4*)&Lts[k][ty * 16 + 12];
    acc[0].x  += a0.x*b.x; acc[0].y  += a0.x*b.y; acc[0].z  += a0.x*b.z; acc[0].w  += a0.x*b.w;
    acc[1].x  += a0.y*b.x; acc[1].y  += a0.y*b.y; acc[1].z  += a0.y*b.z; acc[1].w  += a0.y*b.w;
    acc[2].x  += a0.z*b.x; acc[2].y  += a0.z*b.y; acc[2].z  += a0.z*b.z; acc[2].w  += a0.z*b.w;
    acc[3].x  += a0.w*b.x; acc[3].y  += a0.w*b.y; acc[3].z  += a0.w*b.z; acc[3].w  += a0.w*b.w;
    acc[4].x  += a1.x*b.x; acc[4].y  += a1.x*b.y; acc[4].z  += a1.x*b.z; acc[4].w  += a1.x*b.w;
    acc[5].x  += a1.y*b.x; acc[5].y  += a1.y*b.y; acc[5].z  += a1.y*b.z; acc[5].w  += a1.y*b.w;
    acc[6].x  += a1.z*b.x; acc[6].y  += a1.z*b.y; acc[6].z  += a1.z*b.z; acc[6].w  += a1.z*b.w;
    acc[7].x  += a1.w*b.x; acc[7].y  += a1.w*b.y; acc[7].z  += a1.w*b.z; acc[7].w  += a1.w*b.w;
    acc[8].x  += a2.x*b.x; acc[8].y  += a2.x*b.y; acc[8].z  += a2.x*b.z; acc[8].w  += a2.x*b.w;
    acc[9].x  += a2.y*b.x; acc[9].y  += a2.y*b.y; acc[9].z  += a2.y*b.z; acc[9].w  += a2.y*b.w;
    acc[10].x += a2.z*b.x; acc[10].y += a2.z*b.y; acc[10].z += a2.z*b.z; acc[10].w += a2.z*b.w;
    acc[11].x += a2.w*b.x; acc[11].y += a2.w*b.y; acc[11].z += a2.w*b.z; acc[11].w += a2.w*b.w;
    acc[12].x += a3.x*b.x; acc[12].y += a3.x*b.y; acc[12].z += a3.x*b.z; acc[12].w += a3.x*b.w;
    acc[13].x += a3.y*b.x; acc[13].y += a3.y*b.y; acc[13].z += a3.y*b.z; acc[13].w += a3.y*b.w;
    acc[14].x += a3.z*b.x; acc[14].y += a3.z*b.y; acc[14].z += a3.z*b.z; acc[14].w += a3.z*b.w;
    acc[15].x += a3.w*b.x; acc[15].y += a3.w*b.y; acc[15].z += a3.w*b.z; acc[15].w += a3.w*b.w;
  }
  const bool colok = (s0 + tx * 4) < N;
  #pragma unroll
  for (int e = 0; e < 16; ++e) {
    int r = r0 + ty * 16 + e;
    if (r < N && colok) {
      float4* p = (float4*)&A[(size_t)r * N + s0 + tx * 4];
      float4 v = *p;
      v.x -= acc[e].x; v.y -= acc[e].y; v.z -= acc[e].z; v.w -= acc[e].w;
      *p = v;
    }
  }
}

// ======================= gate + top-k + effective weights =======================
__global__ void select_kernel(const void* __restrict__ flagsraw, const double* __restrict__ scores,
                              const float* __restrict__ w1, const float* __restrict__ b1,
                              const float* __restrict__ w2, const float* __restrict__ b2,
                              int* __restrict__ topidx, float* __restrict__ misc,
                              float* __restrict__ out_tail) {
  if (threadIdx.x != 0 || blockIdx.x != 0) return;
  const unsigned char* fb = (const unsigned char*)flagsraw;
  bool nonbin = false, off4 = false;
  for (int i = 0; i < 16; ++i) {
    if (fb[i] > 1) nonbin = true;
    if ((i & 3) && fb[i]) off4 = true;
  }
  int f[16]; int nact = 0;
  for (int i = 0; i < 16; ++i) {
    int v;
    if (nonbin)      v = (((const float*)flagsraw)[i] != 0.0f);
    else if (off4)   v = (fb[i] != 0);
    else             v = (((const int*)flagsraw)[i] != 0);
    f[i] = v; nact += v;
  }
  int gate = (nact >= 4) ? 1 : 0;   // THRESH = 4
  double sc[16];
  for (int i = 0; i < 16; ++i) sc[i] = f[i] ? scores[i] : -1.0e300;
  bool used[16] = {};
  for (int k = 0; k < 8; ++k) {     // descending, ties -> lowest index (lax.top_k)
    int bi = -1; double bv = 0.0;
    for (int i = 0; i < 16; ++i)
      if (!used[i] && (bi < 0 || sc[i] > bv)) { bv = sc[i]; bi = i; }
    used[bi] = true;
    topidx[k] = bi;
  }
  for (int cC = 0; cC < 10; ++cC) {
    float s = 0.0f;
    for (int h = 0; h < 32; ++h) s += w2[h] * w1[h * 10 + cC];
    misc[cC] = s;
  }
  float be = 0.0f;
  for (int h = 0; h < 32; ++h) be += w2[h] * b1[h];
  be += b2[0];
  misc[10] = be;
  ((int*)misc)[12] = gate;
  *out_tail = gate ? 1.0f : 0.0f;
}

// ======================= build combined right-hand matrices M0..M2 =======================
__global__ __launch_bounds__(256) void build_m_kernel(const float* __restrict__ x,
                                                      const int* __restrict__ topidx,
                                                      const float* __restrict__ misc,
                                                      float* __restrict__ M) {
  int i = blockIdx.x * 256 + threadIdx.x;   // 262144 float4 positions
  const float4* T1 = (const float4*)(x + (size_t)topidx[1] * NN);
  const float4* T2 = (const float4*)(x + (size_t)topidx[2] * NN);
  const float4* T3 = (const float4*)(x + (size_t)topidx[3] * NN);
  float w0 = misc[0], w1_ = misc[1], w2_ = misc[2], w3_ = misc[3], w4_ = misc[4], w5_ = misc[5];
  float4 t1 = T1[i], t2 = T2[i], t3 = T3[i];
  float4 m0, m1, m2;
  m0.x = w0 * t1.x + w1_ * t2.x + w2_ * t3.x;
  m0.y = w0 * t1.y + w1_ * t2.y + w2_ * t3.y;
  m0.z = w0 * t1.z + w1_ * t2.z + w2_ * t3.z;
  m0.w = w0 * t1.w + w1_ * t2.w + w2_ * t3.w;
  m1.x = w3_ * t2.x + w4_ * t3.x;
  m1.y = w3_ * t2.y + w4_ * t3.y;
  m1.z = w3_ * t2.z + w4_ * t3.z;
  m1.w = w3_ * t2.w + w4_ * t3.w;
  m2.x = w5_ * t3.x;  m2.y = w5_ * t3.y;  m2.z = w5_ * t3.z;  m2.w = w5_ * t3.w;
  ((float4*)M)[i] = m0;
  ((float4*)(M + NN))[i] = m1;
  ((float4*)(M + 2 * (size_t)NN))[i] = m2;
}

// ======================= split-K final GEMM: P[chunk] = A_chunk @ B_chunk ==========
// VERIFIED round-3 kernel, unchanged.
__global__ __launch_bounds__(256) void final_gemm_kernel(const float* __restrict__ x,
                                                         const float* __restrict__ M,
                                                         const int* __restrict__ topidx,
                                                         float* __restrict__ P) {
  const int chunk = blockIdx.x >> 8;   // 0..5
  const int t  = blockIdx.x & 255;
  const int tr = t >> 4, tc = t & 15;
  const int mi  = chunk >> 1;
  const int k0b = (chunk & 1) << 9;    // 0 or 512
  const float* A = x + (size_t)topidx[mi] * NN;
  const float* B = M + (size_t)mi * NN;
  __shared__ float As[32][68];   // A^T fragment: As[k][r], float4-aligned stride
  __shared__ float Bs[32][68];
  const int ty = threadIdx.x >> 4, tx = threadIdx.x & 15;
  float acc[4][4] = {};
  for (int k0 = k0b; k0 < k0b + 512; k0 += 32) {
    for (int idx = threadIdx.x; idx < 2048; idx += 256) {
      int r = idx >> 5, k = idx & 31;
      As[k][r] = A[(size_t)(tr * 64 + r) * N + k0 + k];
    }
    for (int idx = threadIdx.x; idx < 2048; idx += 256) {
      int k = idx >> 6, cc = idx & 63;
      Bs[k][cc] = B[(size_t)(k0 + k) * N + tc * 64 + cc];
    }
    __syncthreads();
    #pragma unroll 8
    for (int k = 0; k < 32; ++k) {
      float4 a = *(const float4*)&As[k][ty * 4];
      float4 b = *(const float4*)&Bs[k][tx * 4];
      acc[0][0] += a.x * b.x; acc[0][1] += a.x * b.y; acc[0][2] += a.x * b.z; acc[0][3] += a.x * b.w;
      acc[1][0] += a.y * b.x; acc[1][1] += a.y * b.y; acc[1][2] += a.y * b.z; acc[1][3] += a.y * b.w;
      acc[2][0] += a.z * b.x; acc[2][1] += a.z * b.y; acc[2][2] += a.z * b.z; acc[2][3] += a.z * b.w;
      acc[3][0] += a.w * b.x; acc[3][1] += a.w * b.y; acc[3][2] += a.w * b.z; acc[3][3] += a.w * b.w;
    }
    __syncthreads();
  }
  float* Pc = P + (size_t)chunk * NN;
  #pragma unroll
  for (int i = 0; i < 4; ++i) {
    size_t r = (size_t)(tr * 64 + ty * 4 + i);
    float4 v = make_float4(acc[i][0], acc[i][1], acc[i][2], acc[i][3]);
    *(float4*)&Pc[r * N + tc * 64 + tx * 4] = v;
  }
}

// ======================= reduce partials + preserve channels + bias ================
__global__ __launch_bounds__(256) void reduce_out_kernel(const float* __restrict__ x,
                                                         const float* __restrict__ P,
                                                         const int* __restrict__ topidx,
                                                         const float* __restrict__ misc,
                                                         float* __restrict__ out) {
  int i = blockIdx.x * 256 + threadIdx.x;   // 262144 float4 positions
  int gate = ((const int*)misc)[12];
  float4* o = (float4*)out;
  if (!gate) { o[i] = make_float4(0.f, 0.f, 0.f, 0.f); return; }
  float w6 = misc[6], w7 = misc[7], w8 = misc[8], w9 = misc[9], be = misc[10];
  float4 p0 = ((const float4*)(x + (size_t)topidx[4] * NN))[i];
  float4 p1 = ((const float4*)(x + (size_t)topidx[5] * NN))[i];
  float4 p2 = ((const float4*)(x + (size_t)topidx[6] * NN))[i];
  float4 p3 = ((const float4*)(x + (size_t)topidx[7] * NN))[i];
  float4 r;
  r.x = be + w6 * p0.x + w7 * p1.x + w8 * p2.x + w9 * p3.x;
  r.y = be + w6 * p0.y + w7 * p1.y + w8 * p2.y + w9 * p3.y;
  r.z = be + w6 * p0.z + w7 * p1.z + w8 * p2.z + w9 * p3.z;
  r.w = be + w6 * p0.w + w7 * p1.w + w8 * p2.w + w9 * p3.w;
  #pragma unroll
  for (int cN = 0; cN < 6; ++cN) {
    float4 q = ((const float4*)(P + (size_t)cN * NN))[i];
    r.x += q.x; r.y += q.y; r.z += q.z; r.w += q.w;
  }
  o[i] = r;
}

// ======================= host =======================
extern "C" void kernel_launch(void* const* d_in, const int* in_sizes, int n_in,
                              void* d_out, int out_size, void* d_ws, size_t ws_size,
                              hipStream_t stream) {
  const float* x  = (const float*)d_in[0];
  const void*  fl = d_in[1];
  const float* w1 = (const float*)d_in[2];
  const float* b1 = (const float*)d_in[3];
  const float* w2 = (const float*)d_in[4];
  const float* b2 = (const float*)d_in[5];
  float* out = (float*)d_out;

  char* ws = (char*)d_ws;
  float* LU = (float*)ws;                                // 64 MB (dead after LU phase)
  float* Mm = (float*)ws;                                // 12 MB, reuses LU space
  float* P  = (float*)(ws + (size_t)12 * 1024 * 1024);   // 24 MB partials, inside old LU
  size_t tail = (size_t)16 * NN * sizeof(float);         // 67,108,864
  double* scores = (double*)(ws + tail);                 // 16 doubles
  int*    ipiv   = (int*)(ws + tail + 256);              // 16*32 ints
  int*    topidx = (int*)(ws + tail + 256 + 2304);       // 8 ints
  float*  misc   = (float*)(ws + tail + 256 + 2304 + 256); // weff[10], beff, gate

  init_kernel<<<1, 64, 0, stream>>>(scores);
  copy_kernel<<<16384, 256, 0, stream>>>((const float4*)x, (float4*)LU);

  for (int c0 = 0; c0 < N; c0 += 32) {
    panel_kernel<<<16, 1024, 0, stream>>>(LU, ipiv, scores, c0);
    int tcols = N - c0 - 32;
    if (tcols > 0) {
      int ncs = (tcols + 255) / 256;
      ptrsm_kernel<<<16 * ncs, 256, 0, stream>>>(LU, ipiv, c0, ncs);
      int nrt = (tcols + 63) / 64;
      update_kernel<<<16 * nrt * ncs, 256, 0, stream>>>(LU, c0, nrt, ncs);
    }
  }

  select_kernel<<<1, 64, 0, stream>>>(fl, scores, w1, b1, w2, b2, topidx, misc, out + NN);
  build_m_kernel<<<1024, 256, 0, stream>>>(x, topidx, misc, Mm);
  final_gemm_kernel<<<1536, 256, 0, stream>>>(x, Mm, topidx, P);
  reduce_out_kernel<<<1024, 256, 0, stream>>>(x, P, topidx, misc, out);
}